// Round 1
// baseline (3160.098 us; speedup 1.0000x reference)
//
#include <hip/hip_runtime.h>
#include <hip/hip_fp16.h>

typedef _Float16 f16;
typedef _Float16 f16x8 __attribute__((ext_vector_type(8)));
typedef _Float16 f16x4 __attribute__((ext_vector_type(4)));
typedef float    f32x4 __attribute__((ext_vector_type(4)));

__device__ __forceinline__ f32x4 mfma16(f16x8 a, f16x8 b, f32x4 c){
  return __builtin_amdgcn_mfma_f32_16x16x32_f16(a, b, c, 0, 0, 0);
}
__device__ __forceinline__ int imin(int a, int b){ return a < b ? a : b; }

// ---------------------------------------------------------------- f32 -> f16
__global__ void cvt_kernel(const float* __restrict__ src, f16* __restrict__ dst, int n4){
  int i = blockIdx.x * 256 + threadIdx.x;
  if (i < n4){
    float4 v = reinterpret_cast<const float4*>(src)[i];
    f16x4 h;
    h[0] = (f16)v.x; h[1] = (f16)v.y; h[2] = (f16)v.z; h[3] = (f16)v.w;
    reinterpret_cast<f16x4*>(dst)[i] = h;
  }
}

// ---------------------------------------------------------------- rel kernel
// grid: 2048 blocks = (bq in [0,128)) x (g in [0,16)), 256 threads (4 waves).
// Each block: 4 batches (48 x-rows), one graph head g.
__global__ __launch_bounds__(256) void krel(
    const f16* __restrict__ xh, const f16* __restrict__ Wth, const f16* __restrict__ Wph,
    const float* __restrict__ bth, const float* __restrict__ bph,
    const float* __restrict__ boxes, float* __restrict__ relw, float* __restrict__ out2)
{
  const int bid  = blockIdx.x;
  const int slot = bid & 7, idx = bid >> 3;          // XCD swizzle: same g stays on one XCD
  const int g    = slot + ((idx >> 7) << 3);
  const int bq   = idx & 127;
  const int tid  = threadIdx.x;
  const int w    = tid >> 6, lane = tid & 63;
  const int l15  = lane & 15, l4 = lane >> 4;

  __shared__ f16 thS[48][264];   // +8 pad to break bank alignment
  __shared__ f16 phS[48][264];

  const f32x4 fz = {0.f, 0.f, 0.f, 0.f};
  f32x4 accT[3][4], accP[3][4];
  #pragma unroll
  for (int mt = 0; mt < 3; ++mt)
    #pragma unroll
    for (int j = 0; j < 4; ++j){ accT[mt][j] = fz; accP[mt][j] = fz; }

  const f16* Ab = xh  + (size_t)(bq*48 + l15)*1024 + l4*8;
  const f16* Tb = Wth + (size_t)(g*256 + w*64 + l15)*1024 + l4*8;
  const f16* Pb = Wph + (size_t)(g*256 + w*64 + l15)*1024 + l4*8;

  for (int kk = 0; kk < 32; ++kk){
    const int f = kk << 5;
    f16x8 a[3], bt[4], bp[4];
    #pragma unroll
    for (int mt = 0; mt < 3; ++mt) a[mt] = *(const f16x8*)(Ab + mt*16*1024 + f);
    #pragma unroll
    for (int j = 0; j < 4; ++j){
      bt[j] = *(const f16x8*)(Tb + j*16*1024 + f);
      bp[j] = *(const f16x8*)(Pb + j*16*1024 + f);
    }
    #pragma unroll
    for (int mt = 0; mt < 3; ++mt)
      #pragma unroll
      for (int j = 0; j < 4; ++j){
        accT[mt][j] = mfma16(a[mt], bt[j], accT[mt][j]);
        accP[mt][j] = mfma16(a[mt], bp[j], accP[mt][j]);
      }
  }

  // epilogue: bias add, stash theta/phi as f16 in LDS
  #pragma unroll
  for (int j = 0; j < 4; ++j){
    const int ko = w*64 + j*16 + l15;
    const float bT = bth[g*256 + ko];
    const float bP = bph[g*256 + ko];
    #pragma unroll
    for (int mt = 0; mt < 3; ++mt)
      #pragma unroll
      for (int r = 0; r < 4; ++r){
        const int row = mt*16 + l4*4 + r;
        thS[row][ko] = (f16)(accT[mt][j][r] + bT);
        phS[row][ko] = (f16)(accP[mt][j][r] + bP);
      }
  }
  __syncthreads();

  // sim + mask + softmax: wave w handles batch bi = w
  const int bi = w;
  const int bglob = bq*4 + bi;
  f32x4 sa = fz;
  const int arow = imin(bi*12 + l15, 47);
  #pragma unroll
  for (int k8 = 0; k8 < 8; ++k8){
    const f16x8 a = *(const f16x8*)(&thS[arow][k8*32 + l4*8]);
    const f16x8 b = *(const f16x8*)(&phS[arow][k8*32 + l4*8]);
    sa = mfma16(a, b, sa);
  }
  const int m  = l15;
  const int mc = imin(m, 11);
  const float4 bxm = *(const float4*)(boxes + (size_t)(bglob*12 + mc)*4);
  const float cxm = (bxm.x + bxm.z)*0.5f, cym = (bxm.y + bxm.w)*0.5f;
  const float sqm = cxm*cxm + cym*cym;
  #pragma unroll
  for (int r = 0; r < 4; ++r){
    const int n  = l4*4 + r;
    const int nc = imin(n, 11);
    const float4 bxn = *(const float4*)(boxes + (size_t)(bglob*12 + nc)*4);
    const float cxn = (bxn.x + bxn.z)*0.5f, cyn = (bxn.y + bxn.w)*0.5f;
    const float sqn = cxn*cxn + cyn*cyn;
    const float dot = cxn*cxm + cyn*cym;
    const float d2  = (sqn - 2.f*dot) + sqm;       // same assoc as reference
    const float dist = sqrtf(fmaxf(d2, 0.f));
    float val = sa[r] * 0.0625f;                   // / sqrt(256)
    if (dist > 0.2f || m >= 12) val = -__builtin_inff();
    float mx = val;
    #pragma unroll
    for (int d = 1; d < 16; d <<= 1) mx = fmaxf(mx, __shfl_xor(mx, d));
    const float e = expf(val - mx);
    float s = e;
    #pragma unroll
    for (int d = 1; d < 16; d <<= 1) s += __shfl_xor(s, d);
    const float rv = e / s;
    if (n < 12 && m < 12){
      relw[((size_t)(bglob*16 + g))*144 + n*12 + m] = rv;
      if (g == 15) out2[(size_t)bglob*144 + n*12 + m] = rv;
    }
  }
}

// ---------------------------------------------------------------- h kernel
// grid: 2048 blocks = (bq,g), 512 threads (8 waves).
// y = x * W_gcn[g]^T (48x1024), h = rel*y, LN over o, relu, atomicAdd to out.
__global__ __launch_bounds__(512) void kh(
    const f16* __restrict__ xh, const f16* __restrict__ Wgh,
    const float* __restrict__ relw, const float* __restrict__ gam,
    const float* __restrict__ bet, float* __restrict__ out1)
{
  const int bid  = blockIdx.x;
  const int slot = bid & 7, idx = bid >> 3;
  const int g    = slot + ((idx >> 7) << 3);
  const int bq   = idx & 127;
  const int tid  = threadIdx.x;
  const int w    = tid >> 6, lane = tid & 63;
  const int l15  = lane & 15, l4 = lane >> 4;

  __shared__ f16   ylds[48][520];     // one 512-o half of y, f16, +8 pad
  __shared__ float rel_s[4][144];
  __shared__ float stats[48][2];

  for (int t = tid; t < 576; t += 512){
    int bi = t / 144, nm = t % 144;
    rel_s[bi][nm] = relw[((size_t)((bq*4 + bi)*16 + g))*144 + nm];
  }

  const f32x4 fz = {0.f, 0.f, 0.f, 0.f};
  f32x4 acc[3][8];
  #pragma unroll
  for (int mt = 0; mt < 3; ++mt)
    #pragma unroll
    for (int j = 0; j < 8; ++j) acc[mt][j] = fz;

  const f16* Ab = xh  + (size_t)(bq*48 + l15)*1024 + l4*8;
  const f16* Bb = Wgh + (size_t)(g*1024 + w*128 + l15)*1024 + l4*8;

  for (int kk = 0; kk < 32; ++kk){
    const int f = kk << 5;
    f16x8 a[3], b[8];
    #pragma unroll
    for (int mt = 0; mt < 3; ++mt) a[mt] = *(const f16x8*)(Ab + mt*16*1024 + f);
    #pragma unroll
    for (int j = 0; j < 8; ++j)   b[j]  = *(const f16x8*)(Bb + j*16*1024 + f);
    #pragma unroll
    for (int mt = 0; mt < 3; ++mt)
      #pragma unroll
      for (int j = 0; j < 8; ++j)
        acc[mt][j] = mfma16(a[mt], b[j], acc[mt][j]);
  }
  __syncthreads();   // rel_s visible; ylds safe to write

  float srow[6], s2row[6];
  #pragma unroll
  for (int i = 0; i < 6; ++i){ srow[i] = 0.f; s2row[i] = 0.f; }

  // two halves of o: write y->LDS, accumulate LN stats
  #pragma unroll
  for (int half = 0; half < 2; ++half){
    if ((w >> 2) == half){
      const int ww = w & 3;
      #pragma unroll
      for (int mt = 0; mt < 3; ++mt)
        #pragma unroll
        for (int j = 0; j < 8; ++j){
          const int o = ww*128 + j*16 + l15;
          #pragma unroll
          for (int r = 0; r < 4; ++r)
            ylds[mt*16 + l4*4 + r][o] = (f16)acc[mt][j][r];
        }
    }
    __syncthreads();
    #pragma unroll
    for (int i = 0; i < 6; ++i){
      const int row = w*6 + i;
      const int bi = row / 12, n = row % 12;
      const float* rl = &rel_s[bi][n*12];
      float h[8];
      #pragma unroll
      for (int t = 0; t < 8; ++t) h[t] = 0.f;
      #pragma unroll
      for (int mm = 0; mm < 12; ++mm){
        const f16x8 yv = *(const f16x8*)(&ylds[bi*12 + mm][lane*8]);
        const float rv = rl[mm];
        #pragma unroll
        for (int t = 0; t < 8; ++t) h[t] = fmaf(rv, (float)yv[t], h[t]);
      }
      float ls = 0.f, l2 = 0.f;
      #pragma unroll
      for (int t = 0; t < 8; ++t){ ls += h[t]; l2 = fmaf(h[t], h[t], l2); }
      srow[i] += ls; s2row[i] += l2;
    }
    __syncthreads();
  }

  // finalize LN stats (wave w owns rows 6w..6w+5)
  #pragma unroll
  for (int i = 0; i < 6; ++i){
    float s = srow[i], s2 = s2row[i];
    #pragma unroll
    for (int d = 1; d < 64; d <<= 1){
      s  += __shfl_xor(s, d);
      s2 += __shfl_xor(s2, d);
    }
    if (lane == 0){ stats[w*6 + i][0] = s; stats[w*6 + i][1] = s2; }
  }
  __syncthreads();

  // output: pass 0 -> half 1 (already in ylds), pass 1 -> rewrite half 0
  #pragma unroll
  for (int pass = 0; pass < 2; ++pass){
    const int half = 1 - pass;
    if (pass == 1){
      if (w < 4){
        #pragma unroll
        for (int mt = 0; mt < 3; ++mt)
          #pragma unroll
          for (int j = 0; j < 8; ++j){
            const int o = w*128 + j*16 + l15;
            #pragma unroll
            for (int r = 0; r < 4; ++r)
              ylds[mt*16 + l4*4 + r][o] = (f16)acc[mt][j][r];
          }
      }
      __syncthreads();
    }
    const int obase = half*512 + lane*8;
    const float4 ga0 = *(const float4*)(gam + (size_t)g*1024 + obase);
    const float4 ga1 = *(const float4*)(gam + (size_t)g*1024 + obase + 4);
    const float4 be0 = *(const float4*)(bet + (size_t)g*1024 + obase);
    const float4 be1 = *(const float4*)(bet + (size_t)g*1024 + obase + 4);
    const float gv[8] = {ga0.x,ga0.y,ga0.z,ga0.w,ga1.x,ga1.y,ga1.z,ga1.w};
    const float bv[8] = {be0.x,be0.y,be0.z,be0.w,be1.x,be1.y,be1.z,be1.w};
    #pragma unroll
    for (int i = 0; i < 6; ++i){
      const int row = w*6 + i;
      const int bi = row / 12, n = row % 12;
      const float* rl = &rel_s[bi][n*12];
      float h[8];
      #pragma unroll
      for (int t = 0; t < 8; ++t) h[t] = 0.f;
      #pragma unroll
      for (int mm = 0; mm < 12; ++mm){
        const f16x8 yv = *(const f16x8*)(&ylds[bi*12 + mm][lane*8]);
        const float rv = rl[mm];
        #pragma unroll
        for (int t = 0; t < 8; ++t) h[t] = fmaf(rv, (float)yv[t], h[t]);
      }
      const float mu  = stats[row][0] * (1.f/1024.f);
      const float var = stats[row][1] * (1.f/1024.f) - mu*mu;
      const float rs  = rsqrtf(var + 1e-5f);
      float* op = out1 + (size_t)(bq*48 + row)*1024 + obase;
      #pragma unroll
      for (int t = 0; t < 8; ++t){
        float v = (h[t] - mu)*rs*gv[t] + bv[t];
        v = fmaxf(v, 0.f);
        atomicAdd(op + t, v);
      }
    }
    if (pass == 0) __syncthreads();
  }
}

// ---------------------------------------------------------------- launcher
extern "C" void kernel_launch(void* const* d_in, const int* in_sizes, int n_in,
                              void* d_out, int out_size, void* d_ws, size_t ws_size,
                              hipStream_t stream)
{
  const float* x_f   = (const float*)d_in[0];
  const float* boxes = (const float*)d_in[1];
  const float* Wt_f  = (const float*)d_in[2];
  const float* bt_f  = (const float*)d_in[3];
  const float* Wp_f  = (const float*)d_in[4];
  const float* bp_f  = (const float*)d_in[5];
  const float* Wg_f  = (const float*)d_in[6];
  const float* gam   = (const float*)d_in[7];
  const float* bet   = (const float*)d_in[8];

  float* out1 = (float*)d_out;
  float* out2 = out1 + (size_t)512*12*1024;

  char* ws = (char*)d_ws;
  f16*  xh   = (f16*)(ws);                      // 12,582,912 B
  f16*  Wth  = (f16*)(ws + 12582912);           //  8,388,608 B
  f16*  Wph  = (f16*)(ws + 20971520);           //  8,388,608 B
  f16*  Wgh  = (f16*)(ws + 29360128);           // 33,554,432 B
  float* relw = (float*)(ws + 62914560);        //  4,718,592 B  (total ~64.5 MiB)

  hipMemsetAsync(out1, 0, (size_t)512*12*1024*sizeof(float), stream);

  cvt_kernel<<<6144,  256, 0, stream>>>(x_f,  xh,  6291456/4);
  cvt_kernel<<<4096,  256, 0, stream>>>(Wt_f, Wth, 4194304/4);
  cvt_kernel<<<4096,  256, 0, stream>>>(Wp_f, Wph, 4194304/4);
  cvt_kernel<<<16384, 256, 0, stream>>>(Wg_f, Wgh, 16777216/4);

  krel<<<2048, 256, 0, stream>>>(xh, Wth, Wph, bt_f, bp_f, boxes, relw, out2);
  kh<<<2048, 512, 0, stream>>>(xh, Wgh, relw, gam, bet, out1);
}